// Round 8
// baseline (578.296 us; speedup 1.0000x reference)
//
#include <hip/hip_runtime.h>

#define PROP_ALPHA 0.1f
#define PROP_KSTEPS 10

typedef _Float16 half_t;
typedef __attribute__((ext_vector_type(4))) _Float16 half4v;
typedef __attribute__((ext_vector_type(8))) _Float16 half8v;

// ---------------- CSR build ----------------

__global__ void hist_kernel(const int* __restrict__ dst, int* __restrict__ degI, int E) {
    int e = blockIdx.x * blockDim.x + threadIdx.x;
    if (e < E) atomicAdd(&degI[dst[e]], 1);
}

// dinv over N+1 (row N = zero sink for pad slots); also zero vA[N]/vB[N]
__global__ void dinvz_kernel(const int* __restrict__ degI, float* __restrict__ dinv,
                             float* __restrict__ vA, float* __restrict__ vB, int N) {
    int i = blockIdx.x * blockDim.x + threadIdx.x;
    if (i < N) {
        float d = (float)(degI[i] + 1);   // + self loop
        dinv[i] = rsqrtf(d);
    } else if (i == N) {
        dinv[N] = 0.0f;
        vA[N] = 0.0f;
        vB[N] = 0.0f;
    }
}

// rows padded to multiple of 8 slots (pad entries -> src N, w[N]=0)
__global__ __launch_bounds__(256) void scan1_kernel(const int* __restrict__ degI,
                                                    int* __restrict__ rowptr,
                                                    int* __restrict__ blockSums, int N) {
    __shared__ int s[256];
    int t = threadIdx.x;
    int idx = blockIdx.x * 256 + t;
    s[t] = (idx < N) ? ((degI[idx] + 7) & ~7) : 0;
    __syncthreads();
    for (int off = 1; off < 256; off <<= 1) {
        int x = (t >= off) ? s[t - off] : 0;
        __syncthreads();
        s[t] += x;
        __syncthreads();
    }
    if (idx < N) rowptr[idx + 1] = s[t];
    if (t == 255) blockSums[blockIdx.x] = s[255];
    if (blockIdx.x == 0 && t == 0) rowptr[0] = 0;
}

__global__ __launch_bounds__(256) void scan2_kernel(int* __restrict__ blockSums, int nB) {
    __shared__ int s[256];
    int t = threadIdx.x;
    s[t] = (t < nB) ? blockSums[t] : 0;
    __syncthreads();
    for (int off = 1; off < 256; off <<= 1) {
        int x = (t >= off) ? s[t - off] : 0;
        __syncthreads();
        s[t] += x;
        __syncthreads();
    }
    if (t < nB) blockSums[t] = (t == 0) ? 0 : s[t - 1];
}

__global__ void scan3_kernel(int* __restrict__ rowptr, const int* __restrict__ blockSums,
                             int N) {
    int idx = blockIdx.x * 256 + threadIdx.x;
    if (idx < N) rowptr[idx + 1] += blockSums[blockIdx.x];
}

// fill edata with the zero-sink index N (pads read w[N] = 0)
__global__ void fillu_kernel(unsigned int* __restrict__ p, unsigned int val, int n) {
    int i = blockIdx.x * blockDim.x + threadIdx.x;
    if (i < n) p[i] = val;
}

// edata[p] = src (u16) — norm is folded into w = dinv.z
__global__ void scatter_kernel(const int* __restrict__ src, const int* __restrict__ dst,
                               const int* __restrict__ rowptr, int* __restrict__ rowctr,
                               unsigned short* __restrict__ edata, int E) {
    int e = blockIdx.x * blockDim.x + threadIdx.x;
    if (e < E) {
        int d = dst[e];
        int p = rowptr[d] + atomicAdd(&rowctr[d], 1);
        edata[p] = (unsigned short)src[e];
    }
}

// ---------------- prep: w0 = (h)(dinv*x), ah' = (h)(alpha*dinv*x); zero row N --

__global__ void prep_kernel(const float* __restrict__ x, const float* __restrict__ dinv,
                            half_t* __restrict__ z16A, half_t* __restrict__ z16B,
                            half_t* __restrict__ ah16, int N) {
    int i = blockIdx.x * blockDim.x + threadIdx.x;   // float4 groups
    int nvec = (N + 1) * 16;
    if (i >= nvec) return;
    int row = i >> 4;
    if (row < N) {
        float4 v = reinterpret_cast<const float4*>(x)[i];
        float di = dinv[row];
        half4v z;
        z.x = (half_t)(di * v.x); z.y = (half_t)(di * v.y);
        z.z = (half_t)(di * v.z); z.w = (half_t)(di * v.w);
        reinterpret_cast<half4v*>(z16A)[i] = z;
        half4v a;
        a.x = (half_t)(PROP_ALPHA * di * v.x); a.y = (half_t)(PROP_ALPHA * di * v.y);
        a.z = (half_t)(PROP_ALPHA * di * v.z); a.w = (half_t)(PROP_ALPHA * di * v.w);
        reinterpret_cast<half4v*>(ah16)[i] = a;
    } else {
        half4v zz = {(half_t)0.f, (half_t)0.f, (half_t)0.f, (half_t)0.f};
        reinterpret_cast<half4v*>(z16A)[i] = zz;   // zero sink row for pads
        reinterpret_cast<half4v*>(z16B)[i] = zz;
    }
}

// ---------------- fused MLP (round-5 staged-weights structure, w-interface) ---
// input w = dinv.z10 (fp16), vw = dinv.v ; z = w/dinv, v = vw/dinv staged.
// h2 = relu(z@W3 + v*b3^T)@W4 + b4 ; outputs w' = (h)(dinv*h2), ah' = (h)(a*dinv*h2).
// Ws 32 KB staged fp32: W3 for layer 1, overwritten by W4 for layer 2.

__global__ __launch_bounds__(256) void fusedmlp_kernel(const half_t* __restrict__ zx,
                                                       const float* __restrict__ vw,
                                                       const float* __restrict__ dinv,
                                                       const float* __restrict__ W3,
                                                       const float* __restrict__ b3,
                                                       const float* __restrict__ W4,
                                                       const float* __restrict__ b4,
                                                       half_t* __restrict__ z16o,
                                                       half_t* __restrict__ ah16o,
                                                       int N) {
    __shared__ float Ws[64 * 128];     // 32 KB: W3 [k][128] then W4 [k][64]
    __shared__ half_t zsT[64 * 36];    // [k][row] fp16, padded stride 36
    __shared__ half_t ts[32 * 132];    // [row][k] fp16, padded stride 132
    __shared__ float vs[32];
    __shared__ float dis[32];
    __shared__ float rds[32];
    int t = threadIdx.x;
    int r0 = blockIdx.x * 32;
    int rows = min(32, N - r0);

    if (t < 32) {
        float di = (t < rows) ? dinv[r0 + t] : 1.0f;
        dis[t] = di;
        rds[t] = 1.0f / di;
        vs[t] = (t < rows) ? vw[r0 + t] / di : 0.0f;
    }
    for (int idx = t; idx < 64 * 128; idx += 256) Ws[idx] = W3[idx];
    __syncthreads();
    for (int idx = t; idx < 32 * 64; idx += 256) {
        int r = idx >> 6, c = idx & 63;
        float val = (r < rows) ? (float)zx[(size_t)(r0 + r) * 64 + c] * rds[r] : 0.0f;
        zsT[c * 36 + r] = (half_t)val;
    }
    __syncthreads();

    // ---- layer 1: ts = relu(z @ W3 + v*b3^T) ----
    {
        int cq = t & 31, rq = t >> 5;
        int cb = cq * 4, rb = rq * 4;
        float4 b3v = *reinterpret_cast<const float4*>(&b3[cb]);
        float a[4][4];
        #pragma unroll
        for (int ri = 0; ri < 4; ++ri) {
            float vv = vs[rb + ri];
            a[ri][0] = vv * b3v.x; a[ri][1] = vv * b3v.y;
            a[ri][2] = vv * b3v.z; a[ri][3] = vv * b3v.w;
        }
        #pragma unroll 4
        for (int k = 0; k < 64; ++k) {
            half4v zh = *reinterpret_cast<const half4v*>(&zsT[k * 36 + rb]);
            float z0 = (float)zh.x, z1 = (float)zh.y, z2 = (float)zh.z, z3 = (float)zh.w;
            float4 wq = *reinterpret_cast<const float4*>(&Ws[k * 128 + cb]);
            a[0][0] += z0 * wq.x; a[0][1] += z0 * wq.y;
            a[0][2] += z0 * wq.z; a[0][3] += z0 * wq.w;
            a[1][0] += z1 * wq.x; a[1][1] += z1 * wq.y;
            a[1][2] += z1 * wq.z; a[1][3] += z1 * wq.w;
            a[2][0] += z2 * wq.x; a[2][1] += z2 * wq.y;
            a[2][2] += z2 * wq.z; a[2][3] += z2 * wq.w;
            a[3][0] += z3 * wq.x; a[3][1] += z3 * wq.y;
            a[3][2] += z3 * wq.z; a[3][3] += z3 * wq.w;
        }
        #pragma unroll
        for (int ri = 0; ri < 4; ++ri) {
            half4v o;
            o.x = (half_t)fmaxf(a[ri][0], 0.0f); o.y = (half_t)fmaxf(a[ri][1], 0.0f);
            o.z = (half_t)fmaxf(a[ri][2], 0.0f); o.w = (half_t)fmaxf(a[ri][3], 0.0f);
            *reinterpret_cast<half4v*>(&ts[(rb + ri) * 132 + cb]) = o;
        }
    }
    __syncthreads();
    for (int idx = t; idx < 128 * 64; idx += 256) Ws[idx] = W4[idx];
    __syncthreads();

    // ---- layer 2: h2 = t @ W4 + b4; emit w' and ah' ----
    {
        int cg2 = t & 15, rg = t >> 4;
        int cb = cg2 * 4, rb = rg * 2;
        float4 b4v = *reinterpret_cast<const float4*>(&b4[cb]);
        float a[2][4];
        #pragma unroll
        for (int ri = 0; ri < 2; ++ri) {
            a[ri][0] = b4v.x; a[ri][1] = b4v.y; a[ri][2] = b4v.z; a[ri][3] = b4v.w;
        }
        #pragma unroll 4
        for (int k = 0; k < 128; ++k) {
            float t0 = (float)ts[rb * 132 + k];
            float t1 = (float)ts[(rb + 1) * 132 + k];
            float4 wq = *reinterpret_cast<const float4*>(&Ws[k * 64 + cb]);
            a[0][0] += t0 * wq.x; a[0][1] += t0 * wq.y;
            a[0][2] += t0 * wq.z; a[0][3] += t0 * wq.w;
            a[1][0] += t1 * wq.x; a[1][1] += t1 * wq.y;
            a[1][2] += t1 * wq.z; a[1][3] += t1 * wq.w;
        }
        #pragma unroll
        for (int ri = 0; ri < 2; ++ri) {
            int r = rb + ri;
            if (r < rows) {
                float di = dis[r];
                size_t base = (size_t)(r0 + r) * 64 + cb;
                half4v o;
                o.x = (half_t)(di * a[ri][0]); o.y = (half_t)(di * a[ri][1]);
                o.z = (half_t)(di * a[ri][2]); o.w = (half_t)(di * a[ri][3]);
                *reinterpret_cast<half4v*>(&z16o[base]) = o;
                half4v ao;
                ao.x = (half_t)(PROP_ALPHA * di * a[ri][0]);
                ao.y = (half_t)(PROP_ALPHA * di * a[ri][1]);
                ao.z = (half_t)(PROP_ALPHA * di * a[ri][2]);
                ao.w = (half_t)(PROP_ALPHA * di * a[ri][3]);
                *reinterpret_cast<half4v*>(&ah16o[base]) = ao;
            }
        }
    }
}

// ---------------- propagation: w-state, group-per-node, 8-deep pipeline ------
// w_new[d] = (1-a)*dinv[d]^2*(sum_{s in N(d)} w[s] + w[d]) + ah'[d].
// 8-lane group = 1 node. Rows padded to x8: per iteration ONE 16 B broadcast
// edata load (8 srcs) + EIGHT row-gathers (8 x 128 B lines) issued back-to-back
// -> 2x the lines in flight vs round 7. No cross-lane reduction.

template <bool WITHV>
__global__ __launch_bounds__(256, 8) void prop_kernel(
        const half_t* __restrict__ zin, const half_t* __restrict__ ah16,
        const int* __restrict__ rowptr, const unsigned short* __restrict__ edata,
        const float* __restrict__ dinv,
        half_t* __restrict__ zout, float* __restrict__ outF,
        const float* __restrict__ vin, float* __restrict__ vout,
        int N, int lastOut) {
    const int t = threadIdx.x;
    const int grp = t >> 3;               // node group 0..31 in block
    const int l8 = t & 7;                 // lane within group
    const int c = l8 << 3;                // channel base (8 ch, 16 B)
    int node = blockIdx.x * 32 + grp;
    if (node >= N) return;                // no barriers below: safe

    int beg = rowptr[node];
    int end = rowptr[node + 1];           // end-beg multiple of 8
    size_t selfbase = (size_t)node * 64 + c;

    half8v wself = *reinterpret_cast<const half8v*>(&zin[selfbase]);
    half8v ahh = *reinterpret_cast<const half8v*>(&ah16[selfbase]);
    float di = dinv[node];

    float acc[8];
    #pragma unroll
    for (int j = 0; j < 8; ++j) acc[j] = (float)wself[j];   // self term
    float vacc = WITHV ? vin[node] : 0.0f;                  // self vw

    const half_t* zc = zin + c;
    for (int e = beg; e < end; e += 8) {
        uint4 ed = *reinterpret_cast<const uint4*>(&edata[e]);  // 8 srcs, bcast
        int s0 = ed.x & 0xFFFF, s1 = (int)(ed.x >> 16);
        int s2 = ed.y & 0xFFFF, s3 = (int)(ed.y >> 16);
        int s4 = ed.z & 0xFFFF, s5 = (int)(ed.z >> 16);
        int s6 = ed.w & 0xFFFF, s7 = (int)(ed.w >> 16);
        half8v z0 = *reinterpret_cast<const half8v*>(zc + (size_t)s0 * 64);
        half8v z1 = *reinterpret_cast<const half8v*>(zc + (size_t)s1 * 64);
        half8v z2 = *reinterpret_cast<const half8v*>(zc + (size_t)s2 * 64);
        half8v z3 = *reinterpret_cast<const half8v*>(zc + (size_t)s3 * 64);
        half8v z4 = *reinterpret_cast<const half8v*>(zc + (size_t)s4 * 64);
        half8v z5 = *reinterpret_cast<const half8v*>(zc + (size_t)s5 * 64);
        half8v z6 = *reinterpret_cast<const half8v*>(zc + (size_t)s6 * 64);
        half8v z7 = *reinterpret_cast<const half8v*>(zc + (size_t)s7 * 64);
        if (WITHV)
            vacc += ((vin[s0] + vin[s1]) + (vin[s2] + vin[s3]))
                  + ((vin[s4] + vin[s5]) + (vin[s6] + vin[s7]));
        #pragma unroll
        for (int j = 0; j < 8; ++j) {
            float p0 = (float)z0[j] + (float)z1[j];
            float p1 = (float)z2[j] + (float)z3[j];
            float p2 = (float)z4[j] + (float)z5[j];
            float p3 = (float)z6[j] + (float)z7[j];
            acc[j] += (p0 + p1) + (p2 + p3);
        }
    }

    const float om = 1.0f - PROP_ALPHA;
    float dd = di * di;
    if (!lastOut) {
        half8v o;
        #pragma unroll
        for (int j = 0; j < 8; ++j)
            o[j] = (half_t)(om * dd * acc[j] + (float)ahh[j]);
        *reinterpret_cast<half8v*>(&zout[selfbase]) = o;
    } else {
        float rd = 1.0f / di;             // z_out = (1-a)*dinv*S + ah'/dinv
        float r[8];
        #pragma unroll
        for (int j = 0; j < 8; ++j)
            r[j] = om * di * acc[j] + (float)ahh[j] * rd;
        float4 o0 = {r[0], r[1], r[2], r[3]};
        float4 o1 = {r[4], r[5], r[6], r[7]};
        *reinterpret_cast<float4*>(&outF[selfbase]) = o0;
        *reinterpret_cast<float4*>(&outF[selfbase + 4]) = o1;
    }
    if (WITHV && l8 == 0)
        vout[node] = om * dd * vacc + PROP_ALPHA * di;
}

// ---------------- launch ----------------

extern "C" void kernel_launch(void* const* d_in, const int* in_sizes, int n_in,
                              void* d_out, int out_size, void* d_ws, size_t ws_size,
                              hipStream_t stream) {
    const float* x  = (const float*)d_in[0];
    const int*   ei = (const int*)d_in[1];
    const float* W3 = (const float*)d_in[2];
    const float* b3 = (const float*)d_in[3];
    const float* W4 = (const float*)d_in[4];
    const float* b4 = (const float*)d_in[5];
    float* out = (float*)d_out;

    int N = in_sizes[0] / 64;   // IN_CH = 64 ; u16 edata requires N < 65536
    int E = in_sizes[1] / 2;
    const int* srcA = ei;
    const int* dstA = ei + E;

    char* ws = (char*)d_ws;
    size_t off = 0;
    auto alloc = [&](size_t bytes) -> void* {
        void* p = ws + off;
        off = (off + bytes + 255) & ~(size_t)255;
        return p;
    };

    int nScanB = (N + 255) / 256;
    size_t slotsMax = (size_t)E + 8 * (size_t)N;    // upper bound incl. x8 padding

    int*    degI   = (int*)alloc((size_t)N * 4);
    int*    rowptr = (int*)alloc(((size_t)N + 1) * 4);
    int*    rowctr = (int*)alloc((size_t)N * 4);
    int*    bsums  = (int*)alloc((size_t)nScanB * 4);
    float*  dinv   = (float*)alloc(((size_t)N + 1) * 4);
    unsigned short* edata = (unsigned short*)alloc(slotsMax * 2 + 16);
    float*  vA     = (float*)alloc(((size_t)N + 1) * 4);
    float*  vB     = (float*)alloc(((size_t)N + 1) * 4);
    half_t* z16A   = (half_t*)alloc(((size_t)N + 1) * 64 * 2);
    half_t* z16B   = (half_t*)alloc(((size_t)N + 1) * 64 * 2);
    half_t* ah16   = (half_t*)alloc(((size_t)N + 1) * 64 * 2);

    hipMemsetAsync(degI, 0, (size_t)N * 4, stream);
    hipMemsetAsync(rowctr, 0, (size_t)N * 4, stream);

    // --- CSR build (rows padded to x8; pads = sink node N) ---
    int nFill = (int)((slotsMax + 1) / 2);
    unsigned int fillv = ((unsigned int)N << 16) | (unsigned int)N;
    fillu_kernel<<<(nFill + 255) / 256, 256, 0, stream>>>((unsigned int*)edata, fillv, nFill);
    hist_kernel<<<(E + 255) / 256, 256, 0, stream>>>(dstA, degI, E);
    dinvz_kernel<<<(N + 256) / 256, 256, 0, stream>>>(degI, dinv, vA, vB, N);
    scan1_kernel<<<nScanB, 256, 0, stream>>>(degI, rowptr, bsums, N);
    scan2_kernel<<<1, 256, 0, stream>>>(bsums, nScanB);
    scan3_kernel<<<nScanB, 256, 0, stream>>>(rowptr, bsums, N);
    scatter_kernel<<<(E + 255) / 256, 256, 0, stream>>>(srcA, dstA, rowptr, rowctr,
                                                        edata, E);

    int nvec = (N + 1) * 16;
    int propBlocks = (N + 31) / 32;        // 1 node / 8-lane group, 32 nodes/block

    // --- phase 1: w = dinv.x prepped; 10 steps; v tracked as vw ---
    prep_kernel<<<(nvec + 255) / 256, 256, 0, stream>>>(x, dinv, z16A, z16B, ah16, N);
    for (int s = 0; s < PROP_KSTEPS; ++s) {
        const half_t* zi = (s & 1) ? z16B : z16A;
        half_t*       zo = (s & 1) ? z16A : z16B;
        const float*  vi = (s == 0) ? dinv : ((s & 1) ? vA : vB);
        float*        vo = (s & 1) ? vB : vA;
        prop_kernel<true><<<propBlocks, 256, 0, stream>>>(
            zi, ah16, rowptr, edata, dinv, zo, nullptr, vi, vo, N, 0);
    }
    // s0 A->B (vo=vA), s1 B->A (vo=vB), ..., s9 B->A (vo=vB): w10 in z16A, vw10 in vB

    // --- MLP: z16A,vB -> z16B = w' = dinv*h2, ah16 = alpha*dinv*h2 ---
    fusedmlp_kernel<<<(N + 31) / 32, 256, 0, stream>>>(z16A, vB, dinv, W3, b3, W4, b4,
                                                       z16B, ah16, N);

    // --- phase 2: 10 steps from z16B; last step writes fp32 out ---
    for (int s = 0; s < PROP_KSTEPS; ++s) {
        const half_t* zi = (s & 1) ? z16A : z16B;
        half_t*       zo = (s & 1) ? z16B : z16A;
        int last = (s == PROP_KSTEPS - 1) ? 1 : 0;
        prop_kernel<false><<<propBlocks, 256, 0, stream>>>(
            zi, ah16, rowptr, edata, dinv, zo, out, nullptr, nullptr, N, last);
    }
}

// Round 9
// 518.057 us; speedup vs baseline: 1.1163x; 1.1163x over previous
//
#include <hip/hip_runtime.h>

#define PROP_ALPHA 0.1f
#define PROP_KSTEPS 10

typedef _Float16 half_t;
typedef __attribute__((ext_vector_type(4))) _Float16 half4v;
typedef __attribute__((ext_vector_type(8))) _Float16 half8v;
typedef __attribute__((ext_vector_type(4))) float f32x4;

// ---------------- CSR build ----------------

__global__ void hist_kernel(const int* __restrict__ dst, int* __restrict__ degI, int E) {
    int e = blockIdx.x * blockDim.x + threadIdx.x;
    if (e < E) atomicAdd(&degI[dst[e]], 1);
}

// dinv over N+1 (row N = zero sink for pad slots); also zero vA[N]/vB[N]
__global__ void dinvz_kernel(const int* __restrict__ degI, float* __restrict__ dinv,
                             float* __restrict__ vA, float* __restrict__ vB, int N) {
    int i = blockIdx.x * blockDim.x + threadIdx.x;
    if (i < N) {
        float d = (float)(degI[i] + 1);   // + self loop
        dinv[i] = rsqrtf(d);
    } else if (i == N) {
        dinv[N] = 0.0f;
        vA[N] = 0.0f;
        vB[N] = 0.0f;
    }
}

// rows padded to multiple of 4 slots (pad entries -> src N, w[N]=0)
__global__ __launch_bounds__(256) void scan1_kernel(const int* __restrict__ degI,
                                                    int* __restrict__ rowptr,
                                                    int* __restrict__ blockSums, int N) {
    __shared__ int s[256];
    int t = threadIdx.x;
    int idx = blockIdx.x * 256 + t;
    s[t] = (idx < N) ? ((degI[idx] + 3) & ~3) : 0;
    __syncthreads();
    for (int off = 1; off < 256; off <<= 1) {
        int x = (t >= off) ? s[t - off] : 0;
        __syncthreads();
        s[t] += x;
        __syncthreads();
    }
    if (idx < N) rowptr[idx + 1] = s[t];
    if (t == 255) blockSums[blockIdx.x] = s[255];
    if (blockIdx.x == 0 && t == 0) rowptr[0] = 0;
}

__global__ __launch_bounds__(256) void scan2_kernel(int* __restrict__ blockSums, int nB) {
    __shared__ int s[256];
    int t = threadIdx.x;
    s[t] = (t < nB) ? blockSums[t] : 0;
    __syncthreads();
    for (int off = 1; off < 256; off <<= 1) {
        int x = (t >= off) ? s[t - off] : 0;
        __syncthreads();
        s[t] += x;
        __syncthreads();
    }
    if (t < nB) blockSums[t] = (t == 0) ? 0 : s[t - 1];
}

__global__ void scan3_kernel(int* __restrict__ rowptr, const int* __restrict__ blockSums,
                             int N) {
    int idx = blockIdx.x * 256 + threadIdx.x;
    if (idx < N) rowptr[idx + 1] += blockSums[blockIdx.x];
}

// fill edata with the zero-sink index N (pads read w[N] = 0)
__global__ void fillu_kernel(unsigned int* __restrict__ p, unsigned int val, int n) {
    int i = blockIdx.x * blockDim.x + threadIdx.x;
    if (i < n) p[i] = val;
}

// edata[p] = src (u16) — norm is folded into w = dinv.z
__global__ void scatter_kernel(const int* __restrict__ src, const int* __restrict__ dst,
                               const int* __restrict__ rowptr, int* __restrict__ rowctr,
                               unsigned short* __restrict__ edata, int E) {
    int e = blockIdx.x * blockDim.x + threadIdx.x;
    if (e < E) {
        int d = dst[e];
        int p = rowptr[d] + atomicAdd(&rowctr[d], 1);
        edata[p] = (unsigned short)src[e];
    }
}

// ---------------- prep: w0 = (h)(dinv*x), ah' = (h)(alpha*dinv*x); zero row N --

__global__ void prep_kernel(const float* __restrict__ x, const float* __restrict__ dinv,
                            half_t* __restrict__ z16A, half_t* __restrict__ z16B,
                            half_t* __restrict__ ah16, int N) {
    int i = blockIdx.x * blockDim.x + threadIdx.x;   // float4 groups
    int nvec = (N + 1) * 16;
    if (i >= nvec) return;
    int row = i >> 4;
    if (row < N) {
        float4 v = reinterpret_cast<const float4*>(x)[i];
        float di = dinv[row];
        half4v z;
        z.x = (half_t)(di * v.x); z.y = (half_t)(di * v.y);
        z.z = (half_t)(di * v.z); z.w = (half_t)(di * v.w);
        reinterpret_cast<half4v*>(z16A)[i] = z;
        half4v a;
        a.x = (half_t)(PROP_ALPHA * di * v.x); a.y = (half_t)(PROP_ALPHA * di * v.y);
        a.z = (half_t)(PROP_ALPHA * di * v.z); a.w = (half_t)(PROP_ALPHA * di * v.w);
        reinterpret_cast<half4v*>(ah16)[i] = a;
    } else {
        half4v zz = {(half_t)0.f, (half_t)0.f, (half_t)0.f, (half_t)0.f};
        reinterpret_cast<half4v*>(z16A)[i] = zz;   // zero sink row for pads
        reinterpret_cast<half4v*>(z16B)[i] = zz;
    }
}

// ---------------- MFMA MLP ----------------
// h2 = relu(z@W3 + v*b3^T)@W4 + b4 via v_mfma_f32_16x16x32_f16.
// Block = 4 waves x 16-node strips (64 nodes). Frag layouts (gfx950):
//   A (16x32): lane holds row=lane&15, k = (lane>>4)*8 + i   (8 contiguous k)
//   B (32x16): lane holds col=lane&15, k = (lane>>4)*8 + i
//   C/D:       lane holds col=lane&15, row=(lane>>4)*4 + reg  [m89-verified]
// v*b3^T folded into MFMA C-init (prop linearity). Weights staged fp16
// TRANSPOSED in LDS, padded strides (72/136 elem) -> <=2-way bank aliasing.
// h1 relu'd into per-wave LDS [16][136], read back as ds_read_b128 A2-frags.

__global__ __launch_bounds__(256) void mfmamlp_kernel(const half_t* __restrict__ zx,
                                                      const float* __restrict__ vw,
                                                      const float* __restrict__ dinv,
                                                      const float* __restrict__ W3,
                                                      const float* __restrict__ b3,
                                                      const float* __restrict__ W4,
                                                      const float* __restrict__ b4,
                                                      half_t* __restrict__ z16o,
                                                      half_t* __restrict__ ah16o,
                                                      int N) {
    __shared__ half_t W3T[128 * 72];       // [outcol][k], pad 64->72
    __shared__ half_t W4T[64 * 136];       // [outcol][k], pad 128->136
    __shared__ half_t h1s[4][16 * 136];    // per-wave [row][k], pad 128->136
    __shared__ float vds[4][16];           // per-wave v = vw/dinv
    __shared__ float dds[4][16];           // per-wave dinv

    int t = threadIdx.x;
    int wv = t >> 6, lane = t & 63;
    int ln16 = lane & 15, kg = lane >> 4;  // kg = k-group 0..3
    int r0w = blockIdx.x * 64 + wv * 16;

    for (int idx = t; idx < 64 * 128; idx += 256) {   // W3 [64k][128c]
        int k = idx >> 7, c = idx & 127;
        W3T[c * 72 + k] = (half_t)W3[idx];
    }
    for (int idx = t; idx < 128 * 64; idx += 256) {   // W4 [128k][64c]
        int k = idx >> 6, c = idx & 63;
        W4T[c * 136 + k] = (half_t)W4[idx];
    }
    if (lane < 16) {
        int r = r0w + lane;
        float di = (r < N) ? dinv[r] : 0.0f;
        dds[wv][lane] = di;
        vds[wv][lane] = (r < N && di > 0.0f) ? vw[r] / di : 0.0f;
    }
    __syncthreads();

    // ---- A1 frags: z = w/dinv, fp16, clamped to sink row N for tail ----
    int rowg = r0w + ln16;
    int rowc = (rowg < N) ? rowg : N;                 // sink row = zeros
    float rds = (rowg < N) ? 1.0f / dinv[rowg] : 0.0f;
    half8v a1[2];
    #pragma unroll
    for (int h = 0; h < 2; ++h) {
        half8v w8 = *reinterpret_cast<const half8v*>(
            &zx[(size_t)rowc * 64 + h * 32 + kg * 8]);
        half8v s;
        #pragma unroll
        for (int j = 0; j < 8; ++j) s[j] = (half_t)((float)w8[j] * rds);
        a1[h] = s;
    }

    // ---- layer 1: h1 = relu(z@W3 + v*b3^T), 8 col-tiles x (K=64) ----
    #pragma unroll
    for (int ct = 0; ct < 8; ++ct) {
        float b3c = b3[ct * 16 + ln16];
        f32x4 acc;
        #pragma unroll
        for (int r = 0; r < 4; ++r) acc[r] = vds[wv][kg * 4 + r] * b3c;
        const half_t* wbase = &W3T[(ct * 16 + ln16) * 72 + kg * 8];
        half8v b10 = *reinterpret_cast<const half8v*>(wbase);
        half8v b11 = *reinterpret_cast<const half8v*>(wbase + 32);
        acc = __builtin_amdgcn_mfma_f32_16x16x32_f16(a1[0], b10, acc, 0, 0, 0);
        acc = __builtin_amdgcn_mfma_f32_16x16x32_f16(a1[1], b11, acc, 0, 0, 0);
        #pragma unroll
        for (int r = 0; r < 4; ++r)
            h1s[wv][(kg * 4 + r) * 136 + ct * 16 + ln16] =
                (half_t)fmaxf(acc[r], 0.0f);
    }
    // intra-wave LDS write->read: compiler inserts lgkmcnt; no barrier needed
    // (h1s is per-wave). But ds_write->ds_read same wave needs the waitcnt only.

    // ---- layer 2: h2 = h1@W4 + b4, 4 col-tiles x (K=128) ----
    #pragma unroll
    for (int ct2 = 0; ct2 < 4; ++ct2) {
        float b4c = b4[ct2 * 16 + ln16];
        f32x4 acc = {b4c, b4c, b4c, b4c};
        #pragma unroll
        for (int kh = 0; kh < 4; ++kh) {
            half8v a2 = *reinterpret_cast<const half8v*>(
                &h1s[wv][ln16 * 136 + kh * 32 + kg * 8]);
            half8v b2 = *reinterpret_cast<const half8v*>(
                &W4T[(ct2 * 16 + ln16) * 136 + kh * 32 + kg * 8]);
            acc = __builtin_amdgcn_mfma_f32_16x16x32_f16(a2, b2, acc, 0, 0, 0);
        }
        #pragma unroll
        for (int r = 0; r < 4; ++r) {
            int row = kg * 4 + r;
            int gr = r0w + row;
            if (gr < N) {
                float di = dds[wv][row];
                float val = acc[r];
                size_t base = (size_t)gr * 64 + ct2 * 16 + ln16;
                z16o[base] = (half_t)(di * val);
                ah16o[base] = (half_t)(PROP_ALPHA * di * val);
            }
        }
    }
}

// ---------------- propagation: w-state, group-per-node (round-7 best) --------
// w_new[d] = (1-a)*dinv[d]^2*(sum_{s in N(d)} w[s] + w[d]) + ah'[d].
// 8-lane group = 1 node. Per 4 edges: ONE ushort4 edata load (group-bcast) +
// 4 row-gathers (each 8x16 B = one 128 B line). No cross-lane reduction.
// Measured ~22 us/step; 8-deep variant regressed (VGPR spill at 256,8 bound).

template <bool WITHV>
__global__ __launch_bounds__(256, 8) void prop_kernel(
        const half_t* __restrict__ zin, const half_t* __restrict__ ah16,
        const int* __restrict__ rowptr, const unsigned short* __restrict__ edata,
        const float* __restrict__ dinv,
        half_t* __restrict__ zout, float* __restrict__ outF,
        const float* __restrict__ vin, float* __restrict__ vout,
        int N, int lastOut) {
    const int t = threadIdx.x;
    const int grp = t >> 3;               // node group 0..31 in block
    const int l8 = t & 7;                 // lane within group
    const int c = l8 << 3;                // channel base (8 ch, 16 B)
    int node = blockIdx.x * 32 + grp;
    if (node >= N) return;                // no barriers below: safe

    int beg = rowptr[node];
    int end = rowptr[node + 1];           // end-beg multiple of 4
    size_t selfbase = (size_t)node * 64 + c;

    half8v wself = *reinterpret_cast<const half8v*>(&zin[selfbase]);
    half8v ahh = *reinterpret_cast<const half8v*>(&ah16[selfbase]);
    float di = dinv[node];

    float acc[8];
    #pragma unroll
    for (int j = 0; j < 8; ++j) acc[j] = (float)wself[j];   // self term
    float vacc = WITHV ? vin[node] : 0.0f;                  // self vw

    for (int e = beg; e < end; e += 4) {
        ushort4 ss = *reinterpret_cast<const ushort4*>(&edata[e]);  // group-bcast
        half8v z0 = *reinterpret_cast<const half8v*>(&zin[(size_t)ss.x * 64 + c]);
        half8v z1 = *reinterpret_cast<const half8v*>(&zin[(size_t)ss.y * 64 + c]);
        half8v z2 = *reinterpret_cast<const half8v*>(&zin[(size_t)ss.z * 64 + c]);
        half8v z3 = *reinterpret_cast<const half8v*>(&zin[(size_t)ss.w * 64 + c]);
        if (WITHV)
            vacc += (vin[ss.x] + vin[ss.y]) + (vin[ss.z] + vin[ss.w]);
        #pragma unroll
        for (int j = 0; j < 8; ++j) {
            float p0 = (float)z0[j] + (float)z1[j];
            float p1 = (float)z2[j] + (float)z3[j];
            acc[j] += p0 + p1;
        }
    }

    const float om = 1.0f - PROP_ALPHA;
    float dd = di * di;
    if (!lastOut) {
        half8v o;
        #pragma unroll
        for (int j = 0; j < 8; ++j)
            o[j] = (half_t)(om * dd * acc[j] + (float)ahh[j]);
        *reinterpret_cast<half8v*>(&zout[selfbase]) = o;
    } else {
        float rd = 1.0f / di;             // z_out = (1-a)*dinv*S + ah'/dinv
        float r[8];
        #pragma unroll
        for (int j = 0; j < 8; ++j)
            r[j] = om * di * acc[j] + (float)ahh[j] * rd;
        float4 o0 = {r[0], r[1], r[2], r[3]};
        float4 o1 = {r[4], r[5], r[6], r[7]};
        *reinterpret_cast<float4*>(&outF[selfbase]) = o0;
        *reinterpret_cast<float4*>(&outF[selfbase + 4]) = o1;
    }
    if (WITHV && l8 == 0)
        vout[node] = om * dd * vacc + PROP_ALPHA * di;
}

// ---------------- launch ----------------

extern "C" void kernel_launch(void* const* d_in, const int* in_sizes, int n_in,
                              void* d_out, int out_size, void* d_ws, size_t ws_size,
                              hipStream_t stream) {
    const float* x  = (const float*)d_in[0];
    const int*   ei = (const int*)d_in[1];
    const float* W3 = (const float*)d_in[2];
    const float* b3 = (const float*)d_in[3];
    const float* W4 = (const float*)d_in[4];
    const float* b4 = (const float*)d_in[5];
    float* out = (float*)d_out;

    int N = in_sizes[0] / 64;   // IN_CH = 64 ; u16 edata requires N < 65536
    int E = in_sizes[1] / 2;
    const int* srcA = ei;
    const int* dstA = ei + E;

    char* ws = (char*)d_ws;
    size_t off = 0;
    auto alloc = [&](size_t bytes) -> void* {
        void* p = ws + off;
        off = (off + bytes + 255) & ~(size_t)255;
        return p;
    };

    int nScanB = (N + 255) / 256;
    size_t slotsMax = (size_t)E + 4 * (size_t)N;    // upper bound incl. x4 padding

    int*    degI   = (int*)alloc((size_t)N * 4);
    int*    rowptr = (int*)alloc(((size_t)N + 1) * 4);
    int*    rowctr = (int*)alloc((size_t)N * 4);
    int*    bsums  = (int*)alloc((size_t)nScanB * 4);
    float*  dinv   = (float*)alloc(((size_t)N + 1) * 4);
    unsigned short* edata = (unsigned short*)alloc(slotsMax * 2 + 16);
    float*  vA     = (float*)alloc(((size_t)N + 1) * 4);
    float*  vB     = (float*)alloc(((size_t)N + 1) * 4);
    half_t* z16A   = (half_t*)alloc(((size_t)N + 1) * 64 * 2);
    half_t* z16B   = (half_t*)alloc(((size_t)N + 1) * 64 * 2);
    half_t* ah16   = (half_t*)alloc(((size_t)N + 1) * 64 * 2);

    hipMemsetAsync(degI, 0, (size_t)N * 4, stream);
    hipMemsetAsync(rowctr, 0, (size_t)N * 4, stream);

    // --- CSR build (rows padded to x4; pads = sink node N) ---
    int nFill = (int)((slotsMax + 1) / 2);
    unsigned int fillv = ((unsigned int)N << 16) | (unsigned int)N;
    fillu_kernel<<<(nFill + 255) / 256, 256, 0, stream>>>((unsigned int*)edata, fillv, nFill);
    hist_kernel<<<(E + 255) / 256, 256, 0, stream>>>(dstA, degI, E);
    dinvz_kernel<<<(N + 256) / 256, 256, 0, stream>>>(degI, dinv, vA, vB, N);
    scan1_kernel<<<nScanB, 256, 0, stream>>>(degI, rowptr, bsums, N);
    scan2_kernel<<<1, 256, 0, stream>>>(bsums, nScanB);
    scan3_kernel<<<nScanB, 256, 0, stream>>>(rowptr, bsums, N);
    scatter_kernel<<<(E + 255) / 256, 256, 0, stream>>>(srcA, dstA, rowptr, rowctr,
                                                        edata, E);

    int nvec = (N + 1) * 16;
    int propBlocks = (N + 31) / 32;        // 1 node / 8-lane group, 32 nodes/block

    // --- phase 1: w = dinv.x prepped; 10 steps; v tracked as vw ---
    prep_kernel<<<(nvec + 255) / 256, 256, 0, stream>>>(x, dinv, z16A, z16B, ah16, N);
    for (int s = 0; s < PROP_KSTEPS; ++s) {
        const half_t* zi = (s & 1) ? z16B : z16A;
        half_t*       zo = (s & 1) ? z16A : z16B;
        const float*  vi = (s == 0) ? dinv : ((s & 1) ? vA : vB);
        float*        vo = (s & 1) ? vB : vA;
        prop_kernel<true><<<propBlocks, 256, 0, stream>>>(
            zi, ah16, rowptr, edata, dinv, zo, nullptr, vi, vo, N, 0);
    }
    // s0 A->B (vo=vA), s1 B->A (vo=vB), ..., s9 B->A (vo=vB): w10 in z16A, vw10 in vB

    // --- MFMA MLP: z16A,vB -> z16B = w' = dinv*h2, ah16 = alpha*dinv*h2 ---
    mfmamlp_kernel<<<(N + 63) / 64, 256, 0, stream>>>(z16A, vB, dinv, W3, b3, W4, b4,
                                                      z16B, ah16, N);

    // --- phase 2: 10 steps from z16B; last step writes fp32 out ---
    for (int s = 0; s < PROP_KSTEPS; ++s) {
        const half_t* zi = (s & 1) ? z16A : z16B;
        half_t*       zo = (s & 1) ? z16B : z16A;
        int last = (s == PROP_KSTEPS - 1) ? 1 : 0;
        prop_kernel<false><<<propBlocks, 256, 0, stream>>>(
            zi, ah16, rowptr, edata, dinv, zo, out, nullptr, nullptr, N, last);
    }
}